// Round 2
// baseline (140.846 us; speedup 1.0000x reference)
//
#include <hip/hip_runtime.h>
#include <hip/hip_cooperative_groups.h>
#include <math.h>

namespace cg = cooperative_groups;

// IIR biquad cascade (K=4), B=64, C=2, L=131072 -> 128 independent rows.
// R7: single cooperative fused kernel.
//  Phase 1: zero-state chunk run; y0[64] kept in VGPRs; end-state d -> LDS
//           window; last 6 threads publish d to a global halo (agent atomics).
//  grid.sync()
//  Phase 2: p = sum N_{m-1} d_{j-m} (R6 math); y[t] = y0[t] + w_t . p with
//           w_t = C A^t precomputed per row (8 FMA/sample, no x re-read, no
//           chunk recompute). w/N read from global with uniform addresses
//           (scalar loads). Store via LDS transpose (LDS free by then).
// Fallbacks: R6 3-kernel path (verified 133us) if cooperative launch is not
// possible; R5 warm-up kernel if workspace is too small.

#define SS   64    // output samples per lane (chunk size)
#define WMAX 384   // max warm-up horizon (calibrated at r=0.95)
#define WMIN 64
#define TT   32    // time-tile staged per LDS round
#define TPB  256   // threads per block (= chunks per block)
#define LSTR 33    // LDS row stride in floats (odd => 2-way = conflict-free)
#define KB   4     // biquads in cascade
#define NL   8     // float4 loads per thread per tile
#define HALO 6     // max chunk lookback (= WMAX/SS)
#define DSTR 9     // padded d stride in LDS (9 coprime 32 => conflict-free)

typedef float vf4 __attribute__((ext_vector_type(4)));

// ===================== prep: A-powers, C*A^t rows, nW =====================
// grid: ceil(rows/4) blocks of 256; each 64-lane group handles one row.
__global__ void iir_prep2_kernel(const float* __restrict__ Bs,
                                 const float* __restrict__ As, int rows,
                                 int* __restrict__ nwrow,
                                 float* __restrict__ nmat,
                                 float* __restrict__ wmat)
{
    __shared__ float mat[4][5][64];   // 0,1: ping-pong; 2: N1; 3: A copy; 4: C/w
    const int grp  = threadIdx.x >> 6;
    const int lane = threadIdx.x & 63;
    const int row  = blockIdx.x * 4 + grp;
    const bool act = (row < rows);

    float b0[KB], b1[KB], b2[KB], na1[KB], na2[KB];
    if (act) {
        const float* Bp = Bs + (size_t)row * KB * 3;
        const float* Ap = As + (size_t)row * KB * 3;
#pragma unroll
        for (int k = 0; k < KB; ++k) {
            float inv = 1.0f / Ap[3 * k];
            b0[k]  =  Bp[3 * k]     * inv;
            b1[k]  =  Bp[3 * k + 1] * inv;
            b2[k]  =  Bp[3 * k + 2] * inv;
            na1[k] = -Ap[3 * k + 1] * inv;
            na2[k] = -Ap[3 * k + 2] * inv;
        }
    }

    float* cur = &mat[grp][0][0];
    float* nxt = &mat[grp][1][0];
    float* n1  = &mat[grp][2][0];
    float* ac  = &mat[grp][3][0];
    float* cw  = &mat[grp][4][0];

    // Build A column-by-column: column j = one filter step from s=e_j, x=0.
    // The cascade's final u for that start state IS the output row C_j.
    if (act && lane < 8) {
        float s[8];
#pragma unroll
        for (int i = 0; i < 8; ++i) s[i] = (i == lane) ? 1.0f : 0.0f;
        float u = 0.0f;
#pragma unroll
        for (int k = 0; k < KB; ++k) {
            float y  = fmaf(b0[k], u, s[2 * k]);
            float t1 = fmaf(na1[k], y, fmaf(b1[k], u, s[2 * k + 1]));
            float t2 = fmaf(na2[k], y, b2[k] * u);
            s[2 * k] = t1; s[2 * k + 1] = t2; u = y;
        }
#pragma unroll
        for (int i = 0; i < 8; ++i) { cur[i * 8 + lane] = s[i]; ac[i * 8 + lane] = s[i]; }
        cw[lane] = u;                              // C_j
    }
    __syncthreads();

    const int i8 = lane >> 3, j8 = lane & 7;

    // A^64 via 6 squarings
    for (int t = 0; t < 6; ++t) {
        float acc = 0.0f;
        if (act) {
#pragma unroll
            for (int m = 0; m < 8; ++m)
                acc = fmaf(cur[i8 * 8 + m], cur[m * 8 + j8], acc);
            nxt[lane] = acc;
        }
        __syncthreads();
        float* t0 = cur; cur = nxt; nxt = t0;
    }

    if (act) {
        float v = cur[lane];                       // N1 = A^64
        n1[lane] = v;
        nmat[(size_t)row * 320 + lane] = v;
    }
    __syncthreads();

    // N_m = N_{m-1} * N1, m = 2..5
    for (int m = 2; m <= 5; ++m) {
        float acc = 0.0f;
        if (act) {
#pragma unroll
            for (int q = 0; q < 8; ++q)
                acc = fmaf(cur[i8 * 8 + q], n1[q * 8 + j8], acc);
            nxt[lane] = acc;
            nmat[(size_t)row * 320 + (m - 1) * 64 + lane] = acc;
        }
        __syncthreads();
        float* t0 = cur; cur = nxt; nxt = t0;
    }
    __syncthreads();

    // w_t = C A^t, t=0..63: lane j owns w[j]; column j of A in regs; shfl for w.
    if (act && lane < 8) {
        float Ac[8];
#pragma unroll
        for (int i = 0; i < 8; ++i) Ac[i] = ac[i * 8 + lane];
        float w = cw[lane];
        float* wm = wmat + (size_t)row * 512;
        for (int t = 0; t < SS; ++t) {
            wm[t * 8 + lane] = w;
            float acc = 0.0f;
#pragma unroll
            for (int i = 0; i < 8; ++i)
                acc = fmaf(__shfl(w, i, 8), Ac[i], acc);
            w = acc;
        }
    }

    // per-row lookback count nW = ceil(W/64), same W formula as R4/R5/R6
    if (act && lane == 0) {
        const float* Ap = As + (size_t)row * KB * 3;
        float r2max = 0.0f;
#pragma unroll
        for (int k = 0; k < KB; ++k) {
            float a0 = Ap[3 * k];
            float a2 = Ap[3 * k + 2] / a0;         // = r^2
            r2max = fmaxf(r2max, a2);
        }
        float rmax = fminf(fmaxf(sqrtf(fmaxf(r2max, 0.f)), 0.20f), 0.955f);
        float Wf = 25.6f / (-logf(rmax));
        int W = ((int)ceilf(Wf) + TT - 1) & ~(TT - 1);
        W = min(max(W, WMIN), WMAX);
        nwrow[row] = (W + SS - 1) / SS;            // 1..6
    }
}

// ===================== fused cooperative kernel ============================
__global__ __launch_bounds__(TPB, 4) void iir_fused_kernel(
    const float* __restrict__ x, const float* __restrict__ Bs,
    const float* __restrict__ As, float* __restrict__ out, int L,
    const float* __restrict__ nmat, const float* __restrict__ wmat,
    const int* __restrict__ nwrow, float* __restrict__ halo)
{
    __shared__ float lds[TPB * LSTR];   // 8448 floats; re-used 3 ways
    const int tid = threadIdx.x;
    const int cpr = L / SS;
    const int bpr = cpr / TPB;
    const int row = blockIdx.x / bpr;
    const int blk = blockIdx.x % bpr;
    const int chunk0 = blk * TPB;

    float b0[KB], b1[KB], b2[KB], na1[KB], na2[KB];
    const float* Bp = Bs + (size_t)row * KB * 3;
    const float* Ap = As + (size_t)row * KB * 3;
#pragma unroll
    for (int k = 0; k < KB; ++k) {
        float inv = 1.0f / Ap[3 * k];
        b0[k]  =  Bp[3 * k]     * inv;
        b1[k]  =  Bp[3 * k + 1] * inv;
        b2[k]  =  Bp[3 * k + 2] * inv;
        na1[k] = -Ap[3 * k + 1] * inv;
        na2[k] = -Ap[3 * k + 2] * inv;
    }

    const float* xrow = x   + (size_t)row * L;
    float*       orow = out + (size_t)row * L;
    float*       myrow = lds + tid * LSTR;

    const int tq = tid >> 3;
    const int p4 = (tid & 7) << 2;
    int off[NL], ldsoff[NL];
#pragma unroll
    for (int l = 0; l < NL; ++l) {
        int j = l * 32 + tq;
        off[l]    = (chunk0 + j) * SS + p4;   // always in [0, L)
        ldsoff[l] = j * LSTR + p4;
    }

    // ---- phase 1: zero-state run, y0 kept in registers ----
    float y0[SS];
    float s1[KB] = {0.f, 0.f, 0.f, 0.f};
    float s2[KB] = {0.f, 0.f, 0.f, 0.f};

    float4 rn[NL];
#pragma unroll
    for (int l = 0; l < NL; ++l)
        rn[l] = *reinterpret_cast<const float4*>(xrow + off[l]);

#pragma unroll
    for (int it = 0; it < SS / TT; ++it) {
        __syncthreads();
#pragma unroll
        for (int l = 0; l < NL; ++l) {
            float* d = lds + ldsoff[l];
            d[0] = rn[l].x; d[1] = rn[l].y; d[2] = rn[l].z; d[3] = rn[l].w;
        }
        if (it + 1 < SS / TT) {
#pragma unroll
            for (int l = 0; l < NL; ++l)
                rn[l] = *reinterpret_cast<const float4*>(xrow + off[l] + (it + 1) * TT);
        }
        __syncthreads();

#pragma unroll
        for (int q = 0; q < TT; ++q) {
            float u = myrow[q];
#pragma unroll
            for (int k = 0; k < KB; ++k) {
                float yv = fmaf(b0[k], u, s1[k]);
                s1[k] = fmaf(na1[k], yv, fmaf(b1[k], u, s2[k]));
                s2[k] = fmaf(na2[k], yv, b2[k] * u);
                u = yv;
            }
            y0[it * TT + q] = u;
        }
    }

    // ---- publish d: LDS window (own) + global halo (last 6 threads) ----
    __syncthreads();                       // all myrow reads done; LDS reused
    float* dl = lds;                       // (TPB+HALO)*DSTR = 2358 floats
#pragma unroll
    for (int k = 0; k < KB; ++k) {
        dl[(tid + HALO) * DSTR + 2 * k]     = s1[k];
        dl[(tid + HALO) * DSTR + 2 * k + 1] = s2[k];
    }
    if (tid >= TPB - HALO) {
        size_t hb = ((size_t)blockIdx.x * HALO + (tid - (TPB - HALO))) * 8;
#pragma unroll
        for (int k = 0; k < KB; ++k) {
            __hip_atomic_store(&halo[hb + 2 * k],     s1[k], __ATOMIC_RELEASE, __HIP_MEMORY_SCOPE_AGENT);
            __hip_atomic_store(&halo[hb + 2 * k + 1], s2[k], __ATOMIC_RELEASE, __HIP_MEMORY_SCOPE_AGENT);
        }
    }

    cg::this_grid().sync();

    if (tid < HALO) {
        float v[8] = {0.f, 0.f, 0.f, 0.f, 0.f, 0.f, 0.f, 0.f};
        if (blk > 0) {
            size_t hb = ((size_t)(blockIdx.x - 1) * HALO + tid) * 8;
#pragma unroll
            for (int i = 0; i < 8; ++i)
                v[i] = __hip_atomic_load(&halo[hb + i], __ATOMIC_ACQUIRE, __HIP_MEMORY_SCOPE_AGENT);
        }
#pragma unroll
        for (int i = 0; i < 8; ++i) dl[tid * DSTR + i] = v[i];
    }
    __syncthreads();

    // ---- exact chunk-start state: p = sum_{m=1..nW} N_{m-1} d_{j-m} ----
    const int nW = nwrow[row];
    const float* Nrow = nmat + (size_t)row * 320;   // uniform -> scalar loads
    const float* Wrow = wmat + (size_t)row * 512;   // uniform -> scalar loads
    float pst[8];
#pragma unroll
    for (int i = 0; i < 8; ++i) pst[i] = dl[(tid + HALO - 1) * DSTR + i];
#pragma unroll 1
    for (int m = 2; m <= nW; ++m) {
        const float* M  = Nrow + (m - 2) * 64;
        const float* dd = dl + (tid + HALO - m) * DSTR;
        float din[8];
#pragma unroll
        for (int q = 0; q < 8; ++q) din[q] = dd[q];
#pragma unroll
        for (int i = 0; i < 8; ++i) {
            float a = pst[i];
#pragma unroll
            for (int q = 0; q < 8; ++q) a = fmaf(M[i * 8 + q], din[q], a);
            pst[i] = a;
        }
    }

    // ---- zero-input correction: y[t] = y0[t] + (C A^t) . p ----
#pragma unroll
    for (int t = 0; t < SS; ++t) {
        float a = y0[t];
#pragma unroll
        for (int i = 0; i < 8; ++i) a = fmaf(Wrow[t * 8 + i], pst[i], a);
        y0[t] = a;
    }

    // ---- store via LDS transpose (whole LDS free again) ----
#pragma unroll
    for (int it = 0; it < SS / TT; ++it) {
        __syncthreads();                   // dl reads done before overwrite
#pragma unroll
        for (int q = 0; q < TT; ++q) myrow[q] = y0[it * TT + q];
        __syncthreads();
#pragma unroll
        for (int l = 0; l < NL; ++l) {
            const float* sp = lds + ldsoff[l];
            vf4 v = { sp[0], sp[1], sp[2], sp[3] };
            __builtin_nontemporal_store(
                v, reinterpret_cast<vf4*>(orow + off[l] + it * TT));
        }
    }
}

// ===================== fallback: R6 two-pass kernels (verified) ============
__global__ __launch_bounds__(TPB, 4) void iir_state_kernel(
    const float* __restrict__ x, const float* __restrict__ Bs,
    const float* __restrict__ As, int L, float* __restrict__ dstate)
{
    __shared__ float lds[TPB * LSTR];
    const int tid = threadIdx.x;
    const int cpr = L / SS;
    const int bpr = cpr / TPB;
    const int row = blockIdx.x / bpr;
    const int chunk0 = (blockIdx.x % bpr) * TPB;

    float b0[KB], b1[KB], b2[KB], na1[KB], na2[KB];
    const float* Bp = Bs + (size_t)row * KB * 3;
    const float* Ap = As + (size_t)row * KB * 3;
#pragma unroll
    for (int k = 0; k < KB; ++k) {
        float inv = 1.0f / Ap[3 * k];
        b0[k]  =  Bp[3 * k]     * inv;
        b1[k]  =  Bp[3 * k + 1] * inv;
        b2[k]  =  Bp[3 * k + 2] * inv;
        na1[k] = -Ap[3 * k + 1] * inv;
        na2[k] = -Ap[3 * k + 2] * inv;
    }

    float s1[KB] = {0.f, 0.f, 0.f, 0.f};
    float s2[KB] = {0.f, 0.f, 0.f, 0.f};

    const float* xrow = x + (size_t)row * L;
    float* myrow = lds + tid * LSTR;

    const int tq = tid >> 3;
    const int p4 = (tid & 7) << 2;
    int off[NL], ldsoff[NL];
#pragma unroll
    for (int l = 0; l < NL; ++l) {
        int j = l * 32 + tq;
        off[l]    = (chunk0 + j) * SS + p4;
        ldsoff[l] = j * LSTR + p4;
    }

    float4 rn[NL];
#pragma unroll
    for (int l = 0; l < NL; ++l)
        rn[l] = *reinterpret_cast<const float4*>(xrow + off[l]);

#pragma unroll
    for (int it = 0; it < SS / TT; ++it) {
        __syncthreads();
#pragma unroll
        for (int l = 0; l < NL; ++l) {
            float* d = lds + ldsoff[l];
            d[0] = rn[l].x; d[1] = rn[l].y; d[2] = rn[l].z; d[3] = rn[l].w;
        }
        if (it + 1 < SS / TT) {
            const int base = (it + 1) * TT;
#pragma unroll
            for (int l = 0; l < NL; ++l)
                rn[l] = *reinterpret_cast<const float4*>(xrow + off[l] + base);
        }
        __syncthreads();

#pragma unroll
        for (int p = 0; p < TT; ++p) {
            float u = myrow[p];
#pragma unroll
            for (int k = 0; k < KB; ++k) {
                float yv = fmaf(b0[k], u, s1[k]);
                s1[k] = fmaf(na1[k], yv, fmaf(b1[k], u, s2[k]));
                s2[k] = fmaf(na2[k], yv, b2[k] * u);
                u = yv;
            }
        }
    }

    float* dp = dstate + ((size_t)row * cpr + chunk0 + tid) * 8;
    float4 d0 = make_float4(s1[0], s2[0], s1[1], s2[1]);
    float4 d1 = make_float4(s1[2], s2[2], s1[3], s2[3]);
    *reinterpret_cast<float4*>(dp)     = d0;
    *reinterpret_cast<float4*>(dp + 4) = d1;
}

__global__ __launch_bounds__(TPB, 4) void iir_out_kernel(
    const float* __restrict__ x, const float* __restrict__ Bs,
    const float* __restrict__ As, float* __restrict__ out, int L,
    const float* __restrict__ dstate, const float* __restrict__ nmat,
    const int* __restrict__ nwrow)
{
    __shared__ float lds[TPB * LSTR];
    const int tid = threadIdx.x;
    const int cpr = L / SS;
    const int bpr = cpr / TPB;
    const int row = blockIdx.x / bpr;
    const int chunk0 = (blockIdx.x % bpr) * TPB;
    const int nW = nwrow[row];

    float b0[KB], b1[KB], b2[KB], na1[KB], na2[KB];
    const float* Bp = Bs + (size_t)row * KB * 3;
    const float* Ap = As + (size_t)row * KB * 3;
#pragma unroll
    for (int k = 0; k < KB; ++k) {
        float inv = 1.0f / Ap[3 * k];
        b0[k]  =  Bp[3 * k]     * inv;
        b1[k]  =  Bp[3 * k + 1] * inv;
        b2[k]  =  Bp[3 * k + 2] * inv;
        na1[k] = -Ap[3 * k + 1] * inv;
        na2[k] = -Ap[3 * k + 2] * inv;
    }

    const float* xrow = x   + (size_t)row * L;
    float*       orow = out + (size_t)row * L;
    float*       myrow = lds + tid * LSTR;

    const int tq = tid >> 3;
    const int p4 = (tid & 7) << 2;
    int off[NL], ldsoff[NL];
#pragma unroll
    for (int l = 0; l < NL; ++l) {
        int j = l * 32 + tq;
        off[l]    = (chunk0 + j) * SS + p4;
        ldsoff[l] = j * LSTR + p4;
    }

    float4 rn[NL];
#pragma unroll
    for (int l = 0; l < NL; ++l)
        rn[l] = *reinterpret_cast<const float4*>(xrow + off[l]);

    float* dl = lds;
    float* nl = lds + (TPB + HALO) * DSTR;
    const float* dbase = dstate + ((size_t)row * cpr + chunk0 - HALO) * 8;
    for (int e = tid; e < (TPB + HALO) * 8; e += TPB) {
        int c  = e >> 3;
        int gi = chunk0 - HALO + c;
        float v = 0.0f;
        if (gi >= 0) v = dbase[e];
        dl[c * DSTR + (e & 7)] = v;
    }
    for (int e = tid; e < 320; e += TPB) nl[e] = nmat[(size_t)row * 320 + e];
    __syncthreads();

    float p[8];
#pragma unroll
    for (int i = 0; i < 8; ++i) p[i] = dl[(tid + HALO - 1) * DSTR + i];
#pragma unroll 1
    for (int m = 2; m <= nW; ++m) {
        const float* M  = nl + (m - 2) * 64;
        const float* dd = dl + (tid + HALO - m) * DSTR;
        float din[8];
#pragma unroll
        for (int q = 0; q < 8; ++q) din[q] = dd[q];
#pragma unroll
        for (int i = 0; i < 8; ++i) {
            float a = p[i];
#pragma unroll
            for (int q = 0; q < 8; ++q) a = fmaf(M[i * 8 + q], din[q], a);
            p[i] = a;
        }
    }
    float s1[KB], s2[KB];
#pragma unroll
    for (int k = 0; k < KB; ++k) { s1[k] = p[2 * k]; s2[k] = p[2 * k + 1]; }

#pragma unroll
    for (int it = 0; it < SS / TT; ++it) {
        __syncthreads();
#pragma unroll
        for (int l = 0; l < NL; ++l) {
            float* d = lds + ldsoff[l];
            d[0] = rn[l].x; d[1] = rn[l].y; d[2] = rn[l].z; d[3] = rn[l].w;
        }
        if (it + 1 < SS / TT) {
            const int base = (it + 1) * TT;
#pragma unroll
            for (int l = 0; l < NL; ++l)
                rn[l] = *reinterpret_cast<const float4*>(xrow + off[l] + base);
        }
        __syncthreads();

#pragma unroll
        for (int q = 0; q < TT; ++q) {
            float u = myrow[q];
#pragma unroll
            for (int k = 0; k < KB; ++k) {
                float yv = fmaf(b0[k], u, s1[k]);
                s1[k] = fmaf(na1[k], yv, fmaf(b1[k], u, s2[k]));
                s2[k] = fmaf(na2[k], yv, b2[k] * u);
                u = yv;
            }
            myrow[q] = u;
        }
        __syncthreads();

        const int base = it * TT;
#pragma unroll
        for (int l = 0; l < NL; ++l) {
            const float* sp = lds + ldsoff[l];
            vf4 v = { sp[0], sp[1], sp[2], sp[3] };
            __builtin_nontemporal_store(
                v, reinterpret_cast<vf4*>(orow + off[l] + base));
        }
    }
}

// ===================== fallback path (R5, proven) ==========================
__global__ void iir_prep_kernel(const float* __restrict__ As, int rows,
                                int* __restrict__ wrow, int* __restrict__ perm)
{
    __shared__ int sw[256];
    const int r = threadIdx.x;
    int W = 0;
    if (r < rows) {
        float r2max = 0.f;
#pragma unroll
        for (int k = 0; k < KB; ++k) {
            float a0 = As[(size_t)r * KB * 3 + 3 * k];
            float a2 = As[(size_t)r * KB * 3 + 3 * k + 2] / a0;
            r2max = fmaxf(r2max, a2);
        }
        float rmax = fminf(fmaxf(sqrtf(fmaxf(r2max, 0.f)), 0.20f), 0.955f);
        float Wf = 25.6f / (-logf(rmax));
        W = ((int)ceilf(Wf) + TT - 1) & ~(TT - 1);
        W = min(max(W, WMIN), WMAX);
        wrow[r] = W;
    }
    sw[r] = W;
    __syncthreads();
    if (r < rows) {
        int rank = 0;
        for (int i = 0; i < rows; ++i)
            rank += (sw[i] > W) || (sw[i] == W && i < r);
        perm[rank] = r;
    }
}

__global__ __launch_bounds__(TPB, 4) void iir_chunks_kernel(
    const float* __restrict__ x, const float* __restrict__ Bs,
    const float* __restrict__ As, float* __restrict__ out, int L,
    const int* __restrict__ wrow, const int* __restrict__ perm)
{
    __shared__ float lds[TPB * LSTR];
    const int tid = threadIdx.x;
    const int bpr = (L / SS) / TPB;
    const int row = perm[blockIdx.x / bpr];
    const int chunk0 = (blockIdx.x % bpr) * TPB;
    const int W = wrow[row];

    float b0[KB], b1[KB], b2[KB], na1[KB], na2[KB];
    const float* Bp = Bs + (size_t)row * KB * 3;
    const float* Ap = As + (size_t)row * KB * 3;
#pragma unroll
    for (int k = 0; k < KB; ++k) {
        float inv = 1.0f / Ap[3 * k];
        b0[k]  =  Bp[3 * k]     * inv;
        b1[k]  =  Bp[3 * k + 1] * inv;
        b2[k]  =  Bp[3 * k + 2] * inv;
        na1[k] = -Ap[3 * k + 1] * inv;
        na2[k] = -Ap[3 * k + 2] * inv;
    }

    float s1[KB] = {0.f, 0.f, 0.f, 0.f};
    float s2[KB] = {0.f, 0.f, 0.f, 0.f};

    const float* xrow = x   + (size_t)row * L;
    float*       orow = out + (size_t)row * L;
    float*       myrow = lds + tid * LSTR;

    const int tq = tid >> 3;
    const int p4 = (tid & 7) << 2;
    int off[NL], ldsoff[NL];
#pragma unroll
    for (int l = 0; l < NL; ++l) {
        int j = l * 32 + tq;
        off[l]    = (chunk0 + j) * SS + p4 - W;
        ldsoff[l] = j * LSTR + p4;
    }

    const int NT = (SS + W) / TT;
    const int WT = W / TT;

    float4 rn[NL];
#pragma unroll
    for (int l = 0; l < NL; ++l) {
        int pos = off[l];
        rn[l] = make_float4(0.f, 0.f, 0.f, 0.f);
        if (pos >= 0) rn[l] = *reinterpret_cast<const float4*>(xrow + pos);
    }

#pragma unroll 1
    for (int it = 0; it < NT; ++it) {
        __syncthreads();
#pragma unroll
        for (int l = 0; l < NL; ++l) {
            float* d = lds + ldsoff[l];
            d[0] = rn[l].x; d[1] = rn[l].y; d[2] = rn[l].z; d[3] = rn[l].w;
        }
        if (it + 1 < NT) {
            const int base = (it + 1) * TT;
#pragma unroll
            for (int l = 0; l < NL; ++l) {
                int pos = off[l] + base;
                rn[l] = make_float4(0.f, 0.f, 0.f, 0.f);
                if (pos >= 0) rn[l] = *reinterpret_cast<const float4*>(xrow + pos);
            }
        }
        __syncthreads();

        if (it < WT) {
#pragma unroll
            for (int p = 0; p < TT; ++p) {
                float u = myrow[p];
#pragma unroll
                for (int k = 0; k < KB; ++k) {
                    float yv = fmaf(b0[k], u, s1[k]);
                    s1[k] = fmaf(na1[k], yv, fmaf(b1[k], u, s2[k]));
                    s2[k] = fmaf(na2[k], yv, b2[k] * u);
                    u = yv;
                }
            }
        } else {
#pragma unroll
            for (int p = 0; p < TT; ++p) {
                float u = myrow[p];
#pragma unroll
                for (int k = 0; k < KB; ++k) {
                    float yv = fmaf(b0[k], u, s1[k]);
                    s1[k] = fmaf(na1[k], yv, fmaf(b1[k], u, s2[k]));
                    s2[k] = fmaf(na2[k], yv, b2[k] * u);
                    u = yv;
                }
                myrow[p] = u;
            }
            __syncthreads();

            const int base = it * TT - W;
#pragma unroll
            for (int l = 0; l < NL; ++l) {
                const float* sp = lds + ldsoff[l];
                vf4 v = { sp[0], sp[1], sp[2], sp[3] };
                __builtin_nontemporal_store(
                    v, reinterpret_cast<vf4*>(orow + off[l] + W + base));
            }
        }
    }
}

// ============================== launch =====================================
extern "C" void kernel_launch(void* const* d_in, const int* in_sizes, int n_in,
                              void* d_out, int out_size, void* d_ws, size_t ws_size,
                              hipStream_t stream) {
    const float* x  = (const float*)d_in[0];   // (B, C, L) f32
    const float* Bs = (const float*)d_in[1];   // (B, C, K, 3) f32
    const float* As = (const float*)d_in[2];   // (B, C, K, 3) f32
    float* out = (float*)d_out;                // (B, C, L) f32

    const int rows = in_sizes[1] / (KB * 3);   // B*C = 128
    const int L    = in_sizes[0] / rows;       // 131072
    const int cpr  = L / SS;                   // 2048 chunks per row
    const int bpr  = cpr / TPB;                // 8 blocks per row
    const int grid = rows * bpr;               // 1024

    // workspace layout
    float* dstate = (float*)d_ws;                              // rows*cpr*8
    float* nmatp  = dstate + (size_t)rows * cpr * 8;           // rows*320
    float* wmatp  = nmatp  + (size_t)rows * 320;               // rows*512
    float* halop  = wmatp  + (size_t)rows * 512;               // grid*HALO*8
    int*   nwrowp = (int*)(halop + (size_t)grid * HALO * 8);   // rows
    const size_t need = (size_t)((char*)(nwrowp + rows) - (char*)d_ws);

    const bool shape_ok = (L % SS) == 0 && bpr * TPB == cpr && ws_size >= need;

    // cooperative residency check (host-side query; graph-capture safe)
    static int coopCap = -2;
    if (coopCap == -2) {
        int mb = 0, dev = 0, cus = 0;
        if (hipOccupancyMaxActiveBlocksPerMultiprocessor(&mb, iir_fused_kernel,
                                                         TPB, 0) != hipSuccess) mb = 0;
        hipGetDevice(&dev);
        if (hipDeviceGetAttribute(&cus, hipDeviceAttributeMultiprocessorCount,
                                  dev) != hipSuccess) cus = 0;
        coopCap = mb * cus;
    }

    if (shape_ok) {
        hipLaunchKernelGGL(iir_prep2_kernel, dim3((rows + 3) / 4), dim3(256), 0,
                           stream, Bs, As, rows, nwrowp, nmatp, wmatp);
        bool done = false;
        if (coopCap >= grid) {
            int Lv = L;
            void* args[] = { (void*)&x, (void*)&Bs, (void*)&As, (void*)&out,
                             (void*)&Lv, (void*)&nmatp, (void*)&wmatp,
                             (void*)&nwrowp, (void*)&halop };
            if (hipLaunchCooperativeKernel(iir_fused_kernel, dim3(grid), dim3(TPB),
                                           args, 0, stream) == hipSuccess)
                done = true;
        }
        if (!done) {   // R6 two-pass fallback (verified)
            hipLaunchKernelGGL(iir_state_kernel, dim3(grid), dim3(TPB), 0,
                               stream, x, Bs, As, L, dstate);
            hipLaunchKernelGGL(iir_out_kernel, dim3(grid), dim3(TPB), 0,
                               stream, x, Bs, As, out, L, dstate, nmatp, nwrowp);
        }
    } else {
        int* wrow = (int*)d_ws;
        int* perm = wrow + rows;
        hipLaunchKernelGGL(iir_prep_kernel, dim3(1), dim3(256), 0, stream,
                           As, rows, wrow, perm);
        hipLaunchKernelGGL(iir_chunks_kernel, dim3(rows * bpr), dim3(TPB), 0,
                           stream, x, Bs, As, out, L, wrow, perm);
    }
}

// Round 3
// 133.907 us; speedup vs baseline: 1.0518x; 1.0518x over previous
//
#include <hip/hip_runtime.h>
#include <hip/hip_cooperative_groups.h>
#include <math.h>

namespace cg = cooperative_groups;

// IIR biquad cascade (K=4), B=64, C=2, L=131072 -> 128 independent rows.
// R8: fused cooperative kernel, no y0-in-registers (R7's y0[64] spilled to
// scratch -> VGPR collapsed to 64, VALUBusy 3.5%, 270us).
//  Phase 1: zero-state chunk run (state only, verified R6 K1 body);
//           d -> LDS window; last 6 threads publish d to global halo.
//  grid.sync()  (phase-2 tile-0 x prefetch issued before it, stays in flight)
//  Phase 2: p = sum N_{m-1} d_{j-m}, then recompute chunk from exact state
//           (verified R6 K2 body; x re-read is L2-hot: same block read it in
//           phase 1). All hot loops are byte-identical to the 60-VGPR R6 code.
// Fallbacks: R6 3-kernel path (verified 133us) if cooperative launch is not
// possible; R5 warm-up kernel if workspace is too small.

#define SS   64    // output samples per lane (chunk size)
#define WMAX 384   // max warm-up horizon (calibrated at r=0.95)
#define WMIN 64
#define TT   32    // time-tile staged per LDS round
#define TPB  256   // threads per block (= chunks per block)
#define LSTR 33    // LDS row stride in floats (odd => 2-way = conflict-free)
#define KB   4     // biquads in cascade
#define NL   8     // float4 loads per thread per tile
#define HALO 6     // max chunk lookback (= WMAX/SS)
#define DSTR 9     // padded d stride in LDS (9 coprime 32 => conflict-free)

typedef float vf4 __attribute__((ext_vector_type(4)));

// ===================== prep: A^64 powers + nW (verified R6) ================
__global__ void iir_prep2_kernel(const float* __restrict__ Bs,
                                 const float* __restrict__ As, int rows,
                                 int* __restrict__ nwrow,
                                 float* __restrict__ nmat)
{
    __shared__ float mat[4][3][64];      // per group: two ping-pong + N1
    const int grp  = threadIdx.x >> 6;
    const int lane = threadIdx.x & 63;
    const int row  = blockIdx.x * 4 + grp;
    const bool act = (row < rows);

    float b0[KB], b1[KB], b2[KB], na1[KB], na2[KB];
    if (act) {
        const float* Bp = Bs + (size_t)row * KB * 3;
        const float* Ap = As + (size_t)row * KB * 3;
#pragma unroll
        for (int k = 0; k < KB; ++k) {
            float inv = 1.0f / Ap[3 * k];
            b0[k]  =  Bp[3 * k]     * inv;
            b1[k]  =  Bp[3 * k + 1] * inv;
            b2[k]  =  Bp[3 * k + 2] * inv;
            na1[k] = -Ap[3 * k + 1] * inv;
            na2[k] = -Ap[3 * k + 2] * inv;
        }
    }

    float* cur = &mat[grp][0][0];
    float* nxt = &mat[grp][1][0];
    float* n1  = &mat[grp][2][0];

    // Build A column-by-column: column j = one filter step from s=e_j, x=0.
    if (act && lane < 8) {
        float s[8];
#pragma unroll
        for (int i = 0; i < 8; ++i) s[i] = (i == lane) ? 1.0f : 0.0f;
        float u = 0.0f;
#pragma unroll
        for (int k = 0; k < KB; ++k) {
            float y  = fmaf(b0[k], u, s[2 * k]);
            float t1 = fmaf(na1[k], y, fmaf(b1[k], u, s[2 * k + 1]));
            float t2 = fmaf(na2[k], y, b2[k] * u);
            s[2 * k] = t1; s[2 * k + 1] = t2; u = y;
        }
#pragma unroll
        for (int i = 0; i < 8; ++i) cur[i * 8 + lane] = s[i];   // A[i][j]
    }
    __syncthreads();

    const int i8 = lane >> 3, j8 = lane & 7;

    // A^64 via 6 squarings
    for (int t = 0; t < 6; ++t) {
        float acc = 0.0f;
        if (act) {
#pragma unroll
            for (int m = 0; m < 8; ++m)
                acc = fmaf(cur[i8 * 8 + m], cur[m * 8 + j8], acc);
            nxt[lane] = acc;
        }
        __syncthreads();
        float* t0 = cur; cur = nxt; nxt = t0;
    }

    if (act) {
        float v = cur[lane];                 // N1 = A^64
        n1[lane] = v;
        nmat[(size_t)row * 320 + lane] = v;
    }
    __syncthreads();

    // N_m = N_{m-1} * N1, m = 2..5
    for (int m = 2; m <= 5; ++m) {
        float acc = 0.0f;
        if (act) {
#pragma unroll
            for (int q = 0; q < 8; ++q)
                acc = fmaf(cur[i8 * 8 + q], n1[q * 8 + j8], acc);
            nxt[lane] = acc;
            nmat[(size_t)row * 320 + (m - 1) * 64 + lane] = acc;
        }
        __syncthreads();
        float* t0 = cur; cur = nxt; nxt = t0;
    }

    // per-row lookback count nW = ceil(W/64), same W formula as R4/R5/R6
    if (act && lane == 0) {
        const float* Ap = As + (size_t)row * KB * 3;
        float r2max = 0.0f;
#pragma unroll
        for (int k = 0; k < KB; ++k) {
            float a0 = Ap[3 * k];
            float a2 = Ap[3 * k + 2] / a0;    // = r^2
            r2max = fmaxf(r2max, a2);
        }
        float rmax = fminf(fmaxf(sqrtf(fmaxf(r2max, 0.f)), 0.20f), 0.955f);
        float Wf = 25.6f / (-logf(rmax));
        int W = ((int)ceilf(Wf) + TT - 1) & ~(TT - 1);
        W = min(max(W, WMIN), WMAX);
        nwrow[row] = (W + SS - 1) / SS;       // 1..6
    }
}

// ===================== fused cooperative kernel (R8) =======================
__global__ __launch_bounds__(TPB, 4) void iir_fused_kernel(
    const float* __restrict__ x, const float* __restrict__ Bs,
    const float* __restrict__ As, float* __restrict__ out, int L,
    const float* __restrict__ nmat, const int* __restrict__ nwrow,
    float* __restrict__ halo)
{
    __shared__ float lds[TPB * LSTR];   // x staging; reused as d window
    const int tid = threadIdx.x;
    const int cpr = L / SS;
    const int bpr = cpr / TPB;
    const int row = blockIdx.x / bpr;
    const int blk = blockIdx.x % bpr;
    const int chunk0 = blk * TPB;

    float b0[KB], b1[KB], b2[KB], na1[KB], na2[KB];
    const float* Bp = Bs + (size_t)row * KB * 3;
    const float* Ap = As + (size_t)row * KB * 3;
#pragma unroll
    for (int k = 0; k < KB; ++k) {
        float inv = 1.0f / Ap[3 * k];
        b0[k]  =  Bp[3 * k]     * inv;
        b1[k]  =  Bp[3 * k + 1] * inv;
        b2[k]  =  Bp[3 * k + 2] * inv;
        na1[k] = -Ap[3 * k + 1] * inv;
        na2[k] = -Ap[3 * k + 2] * inv;
    }

    const float* xrow = x   + (size_t)row * L;
    float*       orow = out + (size_t)row * L;
    float*       myrow = lds + tid * LSTR;

    const int tq = tid >> 3;
    const int p4 = (tid & 7) << 2;
    int off[NL], ldsoff[NL];
#pragma unroll
    for (int l = 0; l < NL; ++l) {
        int j = l * 32 + tq;
        off[l]    = (chunk0 + j) * SS + p4;   // always in [0, L)
        ldsoff[l] = j * LSTR + p4;
    }

    // ---- phase 1: zero-state run, state only (verified R6 K1 body) ----
    float s1[KB] = {0.f, 0.f, 0.f, 0.f};
    float s2[KB] = {0.f, 0.f, 0.f, 0.f};

    float4 rn[NL];
#pragma unroll
    for (int l = 0; l < NL; ++l)
        rn[l] = *reinterpret_cast<const float4*>(xrow + off[l]);

#pragma unroll
    for (int it = 0; it < SS / TT; ++it) {
        __syncthreads();
#pragma unroll
        for (int l = 0; l < NL; ++l) {
            float* d = lds + ldsoff[l];
            d[0] = rn[l].x; d[1] = rn[l].y; d[2] = rn[l].z; d[3] = rn[l].w;
        }
        if (it + 1 < SS / TT) {
            const int base = (it + 1) * TT;
#pragma unroll
            for (int l = 0; l < NL; ++l)
                rn[l] = *reinterpret_cast<const float4*>(xrow + off[l] + base);
        }
        __syncthreads();

#pragma unroll
        for (int p = 0; p < TT; ++p) {
            float u = myrow[p];
#pragma unroll
            for (int k = 0; k < KB; ++k) {
                float yv = fmaf(b0[k], u, s1[k]);
                s1[k] = fmaf(na1[k], yv, fmaf(b1[k], u, s2[k]));
                s2[k] = fmaf(na2[k], yv, b2[k] * u);
                u = yv;
            }
        }
    }

    // ---- publish d: LDS window (own) + global halo (last 6 threads) ----
    __syncthreads();                       // all myrow reads done; LDS reused
    float* dl = lds;                       // (TPB+HALO)*DSTR = 2358 floats
#pragma unroll
    for (int k = 0; k < KB; ++k) {
        dl[(tid + HALO) * DSTR + 2 * k]     = s1[k];
        dl[(tid + HALO) * DSTR + 2 * k + 1] = s2[k];
    }
    if (tid >= TPB - HALO) {
        size_t hb = ((size_t)blockIdx.x * HALO + (tid - (TPB - HALO))) * 8;
#pragma unroll
        for (int k = 0; k < KB; ++k) {
            __hip_atomic_store(&halo[hb + 2 * k],     s1[k], __ATOMIC_RELEASE, __HIP_MEMORY_SCOPE_AGENT);
            __hip_atomic_store(&halo[hb + 2 * k + 1], s2[k], __ATOMIC_RELEASE, __HIP_MEMORY_SCOPE_AGENT);
        }
    }

    // ---- phase-2 tile-0 x prefetch: in flight across the grid sync ----
#pragma unroll
    for (int l = 0; l < NL; ++l)
        rn[l] = *reinterpret_cast<const float4*>(xrow + off[l]);

    cg::this_grid().sync();

    if (tid < HALO) {
        float v[8] = {0.f, 0.f, 0.f, 0.f, 0.f, 0.f, 0.f, 0.f};
        if (blk > 0) {
            size_t hb = ((size_t)(blockIdx.x - 1) * HALO + tid) * 8;
#pragma unroll
            for (int i = 0; i < 8; ++i)
                v[i] = __hip_atomic_load(&halo[hb + i], __ATOMIC_ACQUIRE, __HIP_MEMORY_SCOPE_AGENT);
        }
#pragma unroll
        for (int i = 0; i < 8; ++i) dl[tid * DSTR + i] = v[i];
    }
    __syncthreads();

    // ---- exact chunk-start state: p = sum_{m=1..nW} N_{m-1} d_{j-m} ----
    const int nW = nwrow[row];
    const float* Nrow = nmat + (size_t)row * 320;   // uniform -> scalar loads
    float pst[8];
#pragma unroll
    for (int i = 0; i < 8; ++i) pst[i] = dl[(tid + HALO - 1) * DSTR + i];
#pragma unroll 1
    for (int m = 2; m <= nW; ++m) {
        const float* M  = Nrow + (m - 2) * 64;
        const float* dd = dl + (tid + HALO - m) * DSTR;
        float din[8];
#pragma unroll
        for (int q = 0; q < 8; ++q) din[q] = dd[q];
#pragma unroll
        for (int i = 0; i < 8; ++i) {
            float a = pst[i];
#pragma unroll
            for (int q = 0; q < 8; ++q) a = fmaf(M[i * 8 + q], din[q], a);
            pst[i] = a;
        }
    }
#pragma unroll
    for (int k = 0; k < KB; ++k) { s1[k] = pst[2 * k]; s2[k] = pst[2 * k + 1]; }

    // ---- phase 2: recompute chunk from exact state (verified R6 K2 body) --
#pragma unroll
    for (int it = 0; it < SS / TT; ++it) {
        __syncthreads();   // fences dl reads before staging overwrite
#pragma unroll
        for (int l = 0; l < NL; ++l) {
            float* d = lds + ldsoff[l];
            d[0] = rn[l].x; d[1] = rn[l].y; d[2] = rn[l].z; d[3] = rn[l].w;
        }
        if (it + 1 < SS / TT) {
            const int base = (it + 1) * TT;
#pragma unroll
            for (int l = 0; l < NL; ++l)
                rn[l] = *reinterpret_cast<const float4*>(xrow + off[l] + base);
        }
        __syncthreads();

#pragma unroll
        for (int q = 0; q < TT; ++q) {
            float u = myrow[q];
#pragma unroll
            for (int k = 0; k < KB; ++k) {
                float yv = fmaf(b0[k], u, s1[k]);
                s1[k] = fmaf(na1[k], yv, fmaf(b1[k], u, s2[k]));
                s2[k] = fmaf(na2[k], yv, b2[k] * u);
                u = yv;
            }
            myrow[q] = u;
        }
        __syncthreads();

        const int base = it * TT;
#pragma unroll
        for (int l = 0; l < NL; ++l) {
            const float* sp = lds + ldsoff[l];
            vf4 v = { sp[0], sp[1], sp[2], sp[3] };
            __builtin_nontemporal_store(
                v, reinterpret_cast<vf4*>(orow + off[l] + base));
        }
    }
}

// ===================== fallback: R6 two-pass kernels (verified) ============
__global__ __launch_bounds__(TPB, 4) void iir_state_kernel(
    const float* __restrict__ x, const float* __restrict__ Bs,
    const float* __restrict__ As, int L, float* __restrict__ dstate)
{
    __shared__ float lds[TPB * LSTR];
    const int tid = threadIdx.x;
    const int cpr = L / SS;
    const int bpr = cpr / TPB;
    const int row = blockIdx.x / bpr;
    const int chunk0 = (blockIdx.x % bpr) * TPB;

    float b0[KB], b1[KB], b2[KB], na1[KB], na2[KB];
    const float* Bp = Bs + (size_t)row * KB * 3;
    const float* Ap = As + (size_t)row * KB * 3;
#pragma unroll
    for (int k = 0; k < KB; ++k) {
        float inv = 1.0f / Ap[3 * k];
        b0[k]  =  Bp[3 * k]     * inv;
        b1[k]  =  Bp[3 * k + 1] * inv;
        b2[k]  =  Bp[3 * k + 2] * inv;
        na1[k] = -Ap[3 * k + 1] * inv;
        na2[k] = -Ap[3 * k + 2] * inv;
    }

    float s1[KB] = {0.f, 0.f, 0.f, 0.f};
    float s2[KB] = {0.f, 0.f, 0.f, 0.f};

    const float* xrow = x + (size_t)row * L;
    float* myrow = lds + tid * LSTR;

    const int tq = tid >> 3;
    const int p4 = (tid & 7) << 2;
    int off[NL], ldsoff[NL];
#pragma unroll
    for (int l = 0; l < NL; ++l) {
        int j = l * 32 + tq;
        off[l]    = (chunk0 + j) * SS + p4;
        ldsoff[l] = j * LSTR + p4;
    }

    float4 rn[NL];
#pragma unroll
    for (int l = 0; l < NL; ++l)
        rn[l] = *reinterpret_cast<const float4*>(xrow + off[l]);

#pragma unroll
    for (int it = 0; it < SS / TT; ++it) {
        __syncthreads();
#pragma unroll
        for (int l = 0; l < NL; ++l) {
            float* d = lds + ldsoff[l];
            d[0] = rn[l].x; d[1] = rn[l].y; d[2] = rn[l].z; d[3] = rn[l].w;
        }
        if (it + 1 < SS / TT) {
            const int base = (it + 1) * TT;
#pragma unroll
            for (int l = 0; l < NL; ++l)
                rn[l] = *reinterpret_cast<const float4*>(xrow + off[l] + base);
        }
        __syncthreads();

#pragma unroll
        for (int p = 0; p < TT; ++p) {
            float u = myrow[p];
#pragma unroll
            for (int k = 0; k < KB; ++k) {
                float yv = fmaf(b0[k], u, s1[k]);
                s1[k] = fmaf(na1[k], yv, fmaf(b1[k], u, s2[k]));
                s2[k] = fmaf(na2[k], yv, b2[k] * u);
                u = yv;
            }
        }
    }

    float* dp = dstate + ((size_t)row * cpr + chunk0 + tid) * 8;
    float4 d0 = make_float4(s1[0], s2[0], s1[1], s2[1]);
    float4 d1 = make_float4(s1[2], s2[2], s1[3], s2[3]);
    *reinterpret_cast<float4*>(dp)     = d0;
    *reinterpret_cast<float4*>(dp + 4) = d1;
}

__global__ __launch_bounds__(TPB, 4) void iir_out_kernel(
    const float* __restrict__ x, const float* __restrict__ Bs,
    const float* __restrict__ As, float* __restrict__ out, int L,
    const float* __restrict__ dstate, const float* __restrict__ nmat,
    const int* __restrict__ nwrow)
{
    __shared__ float lds[TPB * LSTR];
    const int tid = threadIdx.x;
    const int cpr = L / SS;
    const int bpr = cpr / TPB;
    const int row = blockIdx.x / bpr;
    const int chunk0 = (blockIdx.x % bpr) * TPB;
    const int nW = nwrow[row];

    float b0[KB], b1[KB], b2[KB], na1[KB], na2[KB];
    const float* Bp = Bs + (size_t)row * KB * 3;
    const float* Ap = As + (size_t)row * KB * 3;
#pragma unroll
    for (int k = 0; k < KB; ++k) {
        float inv = 1.0f / Ap[3 * k];
        b0[k]  =  Bp[3 * k]     * inv;
        b1[k]  =  Bp[3 * k + 1] * inv;
        b2[k]  =  Bp[3 * k + 2] * inv;
        na1[k] = -Ap[3 * k + 1] * inv;
        na2[k] = -Ap[3 * k + 2] * inv;
    }

    const float* xrow = x   + (size_t)row * L;
    float*       orow = out + (size_t)row * L;
    float*       myrow = lds + tid * LSTR;

    const int tq = tid >> 3;
    const int p4 = (tid & 7) << 2;
    int off[NL], ldsoff[NL];
#pragma unroll
    for (int l = 0; l < NL; ++l) {
        int j = l * 32 + tq;
        off[l]    = (chunk0 + j) * SS + p4;
        ldsoff[l] = j * LSTR + p4;
    }

    float4 rn[NL];
#pragma unroll
    for (int l = 0; l < NL; ++l)
        rn[l] = *reinterpret_cast<const float4*>(xrow + off[l]);

    float* dl = lds;
    float* nl = lds + (TPB + HALO) * DSTR;
    const float* dbase = dstate + ((size_t)row * cpr + chunk0 - HALO) * 8;
    for (int e = tid; e < (TPB + HALO) * 8; e += TPB) {
        int c  = e >> 3;
        int gi = chunk0 - HALO + c;
        float v = 0.0f;
        if (gi >= 0) v = dbase[e];
        dl[c * DSTR + (e & 7)] = v;
    }
    for (int e = tid; e < 320; e += TPB) nl[e] = nmat[(size_t)row * 320 + e];
    __syncthreads();

    float p[8];
#pragma unroll
    for (int i = 0; i < 8; ++i) p[i] = dl[(tid + HALO - 1) * DSTR + i];
#pragma unroll 1
    for (int m = 2; m <= nW; ++m) {
        const float* M  = nl + (m - 2) * 64;
        const float* dd = dl + (tid + HALO - m) * DSTR;
        float din[8];
#pragma unroll
        for (int q = 0; q < 8; ++q) din[q] = dd[q];
#pragma unroll
        for (int i = 0; i < 8; ++i) {
            float a = p[i];
#pragma unroll
            for (int q = 0; q < 8; ++q) a = fmaf(M[i * 8 + q], din[q], a);
            p[i] = a;
        }
    }
    float s1[KB], s2[KB];
#pragma unroll
    for (int k = 0; k < KB; ++k) { s1[k] = p[2 * k]; s2[k] = p[2 * k + 1]; }

#pragma unroll
    for (int it = 0; it < SS / TT; ++it) {
        __syncthreads();
#pragma unroll
        for (int l = 0; l < NL; ++l) {
            float* d = lds + ldsoff[l];
            d[0] = rn[l].x; d[1] = rn[l].y; d[2] = rn[l].z; d[3] = rn[l].w;
        }
        if (it + 1 < SS / TT) {
            const int base = (it + 1) * TT;
#pragma unroll
            for (int l = 0; l < NL; ++l)
                rn[l] = *reinterpret_cast<const float4*>(xrow + off[l] + base);
        }
        __syncthreads();

#pragma unroll
        for (int q = 0; q < TT; ++q) {
            float u = myrow[q];
#pragma unroll
            for (int k = 0; k < KB; ++k) {
                float yv = fmaf(b0[k], u, s1[k]);
                s1[k] = fmaf(na1[k], yv, fmaf(b1[k], u, s2[k]));
                s2[k] = fmaf(na2[k], yv, b2[k] * u);
                u = yv;
            }
            myrow[q] = u;
        }
        __syncthreads();

        const int base = it * TT;
#pragma unroll
        for (int l = 0; l < NL; ++l) {
            const float* sp = lds + ldsoff[l];
            vf4 v = { sp[0], sp[1], sp[2], sp[3] };
            __builtin_nontemporal_store(
                v, reinterpret_cast<vf4*>(orow + off[l] + base));
        }
    }
}

// ===================== fallback path (R5, proven) ==========================
__global__ void iir_prep_kernel(const float* __restrict__ As, int rows,
                                int* __restrict__ wrow, int* __restrict__ perm)
{
    __shared__ int sw[256];
    const int r = threadIdx.x;
    int W = 0;
    if (r < rows) {
        float r2max = 0.f;
#pragma unroll
        for (int k = 0; k < KB; ++k) {
            float a0 = As[(size_t)r * KB * 3 + 3 * k];
            float a2 = As[(size_t)r * KB * 3 + 3 * k + 2] / a0;
            r2max = fmaxf(r2max, a2);
        }
        float rmax = fminf(fmaxf(sqrtf(fmaxf(r2max, 0.f)), 0.20f), 0.955f);
        float Wf = 25.6f / (-logf(rmax));
        W = ((int)ceilf(Wf) + TT - 1) & ~(TT - 1);
        W = min(max(W, WMIN), WMAX);
        wrow[r] = W;
    }
    sw[r] = W;
    __syncthreads();
    if (r < rows) {
        int rank = 0;
        for (int i = 0; i < rows; ++i)
            rank += (sw[i] > W) || (sw[i] == W && i < r);
        perm[rank] = r;
    }
}

__global__ __launch_bounds__(TPB, 4) void iir_chunks_kernel(
    const float* __restrict__ x, const float* __restrict__ Bs,
    const float* __restrict__ As, float* __restrict__ out, int L,
    const int* __restrict__ wrow, const int* __restrict__ perm)
{
    __shared__ float lds[TPB * LSTR];
    const int tid = threadIdx.x;
    const int bpr = (L / SS) / TPB;
    const int row = perm[blockIdx.x / bpr];
    const int chunk0 = (blockIdx.x % bpr) * TPB;
    const int W = wrow[row];

    float b0[KB], b1[KB], b2[KB], na1[KB], na2[KB];
    const float* Bp = Bs + (size_t)row * KB * 3;
    const float* Ap = As + (size_t)row * KB * 3;
#pragma unroll
    for (int k = 0; k < KB; ++k) {
        float inv = 1.0f / Ap[3 * k];
        b0[k]  =  Bp[3 * k]     * inv;
        b1[k]  =  Bp[3 * k + 1] * inv;
        b2[k]  =  Bp[3 * k + 2] * inv;
        na1[k] = -Ap[3 * k + 1] * inv;
        na2[k] = -Ap[3 * k + 2] * inv;
    }

    float s1[KB] = {0.f, 0.f, 0.f, 0.f};
    float s2[KB] = {0.f, 0.f, 0.f, 0.f};

    const float* xrow = x   + (size_t)row * L;
    float*       orow = out + (size_t)row * L;
    float*       myrow = lds + tid * LSTR;

    const int tq = tid >> 3;
    const int p4 = (tid & 7) << 2;
    int off[NL], ldsoff[NL];
#pragma unroll
    for (int l = 0; l < NL; ++l) {
        int j = l * 32 + tq;
        off[l]    = (chunk0 + j) * SS + p4 - W;
        ldsoff[l] = j * LSTR + p4;
    }

    const int NT = (SS + W) / TT;
    const int WT = W / TT;

    float4 rn[NL];
#pragma unroll
    for (int l = 0; l < NL; ++l) {
        int pos = off[l];
        rn[l] = make_float4(0.f, 0.f, 0.f, 0.f);
        if (pos >= 0) rn[l] = *reinterpret_cast<const float4*>(xrow + pos);
    }

#pragma unroll 1
    for (int it = 0; it < NT; ++it) {
        __syncthreads();
#pragma unroll
        for (int l = 0; l < NL; ++l) {
            float* d = lds + ldsoff[l];
            d[0] = rn[l].x; d[1] = rn[l].y; d[2] = rn[l].z; d[3] = rn[l].w;
        }
        if (it + 1 < NT) {
            const int base = (it + 1) * TT;
#pragma unroll
            for (int l = 0; l < NL; ++l) {
                int pos = off[l] + base;
                rn[l] = make_float4(0.f, 0.f, 0.f, 0.f);
                if (pos >= 0) rn[l] = *reinterpret_cast<const float4*>(xrow + pos);
            }
        }
        __syncthreads();

        if (it < WT) {
#pragma unroll
            for (int p = 0; p < TT; ++p) {
                float u = myrow[p];
#pragma unroll
                for (int k = 0; k < KB; ++k) {
                    float yv = fmaf(b0[k], u, s1[k]);
                    s1[k] = fmaf(na1[k], yv, fmaf(b1[k], u, s2[k]));
                    s2[k] = fmaf(na2[k], yv, b2[k] * u);
                    u = yv;
                }
            }
        } else {
#pragma unroll
            for (int p = 0; p < TT; ++p) {
                float u = myrow[p];
#pragma unroll
                for (int k = 0; k < KB; ++k) {
                    float yv = fmaf(b0[k], u, s1[k]);
                    s1[k] = fmaf(na1[k], yv, fmaf(b1[k], u, s2[k]));
                    s2[k] = fmaf(na2[k], yv, b2[k] * u);
                    u = yv;
                }
                myrow[p] = u;
            }
            __syncthreads();

            const int base = it * TT - W;
#pragma unroll
            for (int l = 0; l < NL; ++l) {
                const float* sp = lds + ldsoff[l];
                vf4 v = { sp[0], sp[1], sp[2], sp[3] };
                __builtin_nontemporal_store(
                    v, reinterpret_cast<vf4*>(orow + off[l] + W + base));
            }
        }
    }
}

// ============================== launch =====================================
extern "C" void kernel_launch(void* const* d_in, const int* in_sizes, int n_in,
                              void* d_out, int out_size, void* d_ws, size_t ws_size,
                              hipStream_t stream) {
    const float* x  = (const float*)d_in[0];   // (B, C, L) f32
    const float* Bs = (const float*)d_in[1];   // (B, C, K, 3) f32
    const float* As = (const float*)d_in[2];   // (B, C, K, 3) f32
    float* out = (float*)d_out;                // (B, C, L) f32

    const int rows = in_sizes[1] / (KB * 3);   // B*C = 128
    const int L    = in_sizes[0] / rows;       // 131072
    const int cpr  = L / SS;                   // 2048 chunks per row
    const int bpr  = cpr / TPB;                // 8 blocks per row
    const int grid = rows * bpr;               // 1024

    // workspace layout (dstate only used by the R6 fallback path)
    float* dstate = (float*)d_ws;                              // rows*cpr*8
    float* nmatp  = dstate + (size_t)rows * cpr * 8;           // rows*320
    float* halop  = nmatp  + (size_t)rows * 320;               // grid*HALO*8
    int*   nwrowp = (int*)(halop + (size_t)grid * HALO * 8);   // rows
    const size_t need = (size_t)((char*)(nwrowp + rows) - (char*)d_ws);

    const bool shape_ok = (L % SS) == 0 && bpr * TPB == cpr && ws_size >= need;

    // cooperative residency check (host-side query; graph-capture safe)
    static int coopCap = -2;
    if (coopCap == -2) {
        int mb = 0, dev = 0, cus = 0;
        if (hipOccupancyMaxActiveBlocksPerMultiprocessor(&mb, iir_fused_kernel,
                                                         TPB, 0) != hipSuccess) mb = 0;
        hipGetDevice(&dev);
        if (hipDeviceGetAttribute(&cus, hipDeviceAttributeMultiprocessorCount,
                                  dev) != hipSuccess) cus = 0;
        coopCap = mb * cus;
    }

    if (shape_ok) {
        hipLaunchKernelGGL(iir_prep2_kernel, dim3((rows + 3) / 4), dim3(256), 0,
                           stream, Bs, As, rows, nwrowp, nmatp);
        bool done = false;
        if (coopCap >= grid) {
            int Lv = L;
            void* args[] = { (void*)&x, (void*)&Bs, (void*)&As, (void*)&out,
                             (void*)&Lv, (void*)&nmatp, (void*)&nwrowp,
                             (void*)&halop };
            if (hipLaunchCooperativeKernel(iir_fused_kernel, dim3(grid), dim3(TPB),
                                           args, 0, stream) == hipSuccess)
                done = true;
        }
        if (!done) {   // R6 two-pass fallback (verified)
            hipLaunchKernelGGL(iir_state_kernel, dim3(grid), dim3(TPB), 0,
                               stream, x, Bs, As, L, dstate);
            hipLaunchKernelGGL(iir_out_kernel, dim3(grid), dim3(TPB), 0,
                               stream, x, Bs, As, out, L, dstate, nmatp, nwrowp);
        }
    } else {
        int* wrow = (int*)d_ws;
        int* perm = wrow + rows;
        hipLaunchKernelGGL(iir_prep_kernel, dim3(1), dim3(256), 0, stream,
                           As, rows, wrow, perm);
        hipLaunchKernelGGL(iir_chunks_kernel, dim3(rows * bpr), dim3(TPB), 0,
                           stream, x, Bs, As, out, L, wrow, perm);
    }
}